// Round 5
// baseline (296.689 us; speedup 1.0000x reference)
//
#include <hip/hip_runtime.h>
#include <hip/hip_bf16.h>
#include <math.h>

#define GLOBAL_AS __attribute__((address_space(1)))
#define LDS_AS __attribute__((address_space(3)))

typedef __bf16 bf16x8 __attribute__((ext_vector_type(8)));
typedef float f32x4 __attribute__((ext_vector_type(4)));

#define N 8192
#define D 1024

__device__ __forceinline__ unsigned short f2bf_rne(float f) {
  unsigned u = __float_as_uint(f);
  unsigned r = u + 0x7FFFu + ((u >> 16) & 1u);
  return (unsigned short)(r >> 16);
}

// Convert z (fp32) -> z_hi + z_lo (bf16 split), and row sums of squares.
// zh and zl are adjacent: zl = zh + N*D, forming a [N][2048] "extended" bf16
// matrix whose gram = hi.hi + hi.lo + lo.hi + lo.lo ~= fp32 gram.
__global__ __launch_bounds__(256) void prep_kernel(
    const float* __restrict__ z, unsigned short* __restrict__ zh,
    unsigned short* __restrict__ zl, float* __restrict__ sq) {
  const int r = blockIdx.x, t = threadIdx.x;
  const float4 v = *(const float4*)(z + (size_t)r * D + t * 4);
  float f[4] = {v.x, v.y, v.z, v.w};
  unsigned short hh[4], ll[4];
  float s = 0.f;
#pragma unroll
  for (int u = 0; u < 4; ++u) {
    float x = f[u];
    s = fmaf(x, x, s);
    unsigned short hb = f2bf_rne(x);
    float hf = __uint_as_float(((unsigned)hb) << 16);
    hh[u] = hb;
    ll[u] = f2bf_rne(x - hf);
  }
  *(ushort4*)(zh + (size_t)r * D + t * 4) = make_ushort4(hh[0], hh[1], hh[2], hh[3]);
  *(ushort4*)(zl + (size_t)r * D + t * 4) = make_ushort4(ll[0], ll[1], ll[2], ll[3]);
  // deterministic block reduction
#pragma unroll
  for (int o = 32; o >= 1; o >>= 1) s += __shfl_down(s, o, 64);
  __shared__ float red[4];
  const int lane = t & 63, wv = t >> 6;
  if (lane == 0) red[wv] = s;
  __syncthreads();
  if (t == 0) sq[r] = ((red[0] + red[1]) + red[2]) + red[3];
}

// Lower-triangle 128x128 tile gram over Kext=2048 + fused KL epilogue.
// Off-diagonal tiles (ib>jb) emit row partials (rows of block ib, slot
// 2*jb+wc) AND column partials (rows of block jb, slot 2*ib+wr). For
// row-block r: direct slots [0,2r+1], transposed [2r+2,127] -> each of the
// 128 slots written exactly once.
// launch_bounds(256,2): 256-reg cap. Caps of 128 (r3) and 170 (r4) both
// forced k-loop scratch spill (WRITE_SIZE 242/126 MB vs 13 MB of outputs).
// Loop live set is ~140-160 unified regs; let the allocator have them.
__global__ __launch_bounds__(256, 2) void gram_kernel(
    const unsigned short* __restrict__ zh,
    const float* __restrict__ sq, const int* __restrict__ idx,
    float* __restrict__ Pws, float* __restrict__ Pz, float* __restrict__ Ppl) {
  __shared__ __align__(16) unsigned short lds[2 * 128 * 32];  // A, B (16 KiB)
  __shared__ float2 lut[12];  // (w, w*Pl) per v3 value; [11] = diff==0 case
  // triangle decode: blockIdx.x = ib*(ib+1)/2 + jb, jb <= ib
  const int t = blockIdx.x;
  int ib = (int)((sqrtf(8.f * (float)t + 1.f) - 1.f) * 0.5f);
  while ((ib + 1) * (ib + 2) / 2 <= t) ++ib;
  while (ib * (ib + 1) / 2 > t) --ib;
  const int jb = t - ib * (ib + 1) / 2;

  const int tid = threadIdx.x;
  const int lane = tid & 63, wv = tid >> 6;
  const int wr = wv >> 1, wc = wv & 1;
  const int r0 = lane & 15, kg = lane >> 4;

  if (tid < 12) {
    const float Pl = (tid == 11) ? 0.f : -2.f * exp2f(-1.5849625007211562f * (float)tid);
    const float w = exp2f(1.4426950408889634f * Pl);
    lut[tid] = make_float2(w, w * Pl);
  }

  // Staging: 4 global_load_lds (16B) per wave per K-step.
  // LDS unit u = 4*r + (c ^ ((r>>1)&3)) (16B units) -> free 2-way read conflict.
  const unsigned short* srcs[4];
  unsigned ldso[4];
#pragma unroll
  for (int inst = 0; inst < 4; ++inst) {
    const int tile = inst >> 1, half = inst & 1;  // tile: 0=A (rows ib), 1=B (rows jb)
    const int ut = wv * 128 + half * 64 + lane;   // 16B unit in tile [0,512)
    const int rr = ut >> 2, cs = ut & 3;
    const int c = cs ^ ((rr >> 1) & 3);
    const int rowg = ((tile == 0) ? ib : jb) * 128 + rr;
    srcs[inst] = zh + (size_t)rowg * D + c * 8;
    ldso[inst] = (unsigned)(tile * 8192 + (wv * 128 + half * 64) * 16);
  }

  f32x4 acc[4][4];
  const f32x4 vz = {0.f, 0.f, 0.f, 0.f};
#pragma unroll
  for (int m = 0; m < 4; ++m)
#pragma unroll
    for (int n = 0; n < 4; ++n) acc[m][n] = vz;

  const int swz = ((r0 >> 1) & 3) ^ kg;
  const unsigned aoff = (unsigned)((wr * 64 + r0) * 64 + swz * 16);
  const unsigned boff = (unsigned)(8192 + (wc * 64 + r0) * 64 + swz * 16);
  char* ldsc = (char*)&lds[0];

  // Kext = 2048 as two 1024-col segments (hi rows then lo rows of the split);
  // pointer-bump addressing, no per-iter 64-bit offset math.
#pragma unroll 1
  for (int seg = 0; seg < 2; ++seg) {
#pragma unroll 1
    for (int ks = 0; ks < 32; ++ks) {
      __syncthreads();
#pragma unroll
      for (int inst = 0; inst < 4; ++inst) {
        __builtin_amdgcn_global_load_lds((const GLOBAL_AS void*)srcs[inst],
                                         (LDS_AS void*)(ldsc + ldso[inst]), 16, 0, 0);
        srcs[inst] += 32;
      }
      __syncthreads();

      bf16x8 a[4], b[4];
#pragma unroll
      for (int m = 0; m < 4; ++m) a[m] = *(const bf16x8*)(ldsc + aoff + m * 1024);
#pragma unroll
      for (int n = 0; n < 4; ++n) b[n] = *(const bf16x8*)(ldsc + boff + n * 1024);
#pragma unroll
      for (int m = 0; m < 4; ++m)
#pragma unroll
        for (int n = 0; n < 4; ++n)
          acc[m][n] = __builtin_amdgcn_mfma_f32_16x16x32_bf16(a[m], b[n], acc[m][n], 0, 0, 0);
    }
#pragma unroll
    for (int inst = 0; inst < 4; ++inst) srcs[inst] += (size_t)N * D - 1024;
  }

  // ---- Epilogue: S = -2*sqrt(max(sq_i+sq_j-2g,0)); padic weights; partials ----
  const int ibase = ib * 128 + wr * 64 + kg * 4;
  const int jbase = jb * 128 + wc * 64 + r0;
  float sqj[4];
  int idxj[4];
#pragma unroll
  for (int n = 0; n < 4; ++n) {
    sqj[n] = sq[jbase + n * 16];
    idxj[n] = idx[jbase + n * 16];
  }
  const int dslot = jb * 2 + wc;
  // column (transposed) accumulators: per n, summed over this lane's (m,q) i-set
  float cws[4] = {0.f, 0.f, 0.f, 0.f};
  float czz[4] = {0.f, 0.f, 0.f, 0.f};
  float cpl[4] = {0.f, 0.f, 0.f, 0.f};
#pragma unroll
  for (int m = 0; m < 4; ++m) {
#pragma unroll
    for (int q = 0; q < 4; ++q) {
      const int i = ibase + m * 16 + q;
      const float sqi = sq[i];
      const int idxi = idx[i];
      float ws = 0.f, zz = 0.f, wpl = 0.f;
#pragma unroll
      for (int n = 0; n < 4; ++n) {
        const int j = jbase + n * 16;
        const float g = acc[m][n][q];
        const float d2 = sqi + sqj[n] - 2.f * g;
        const float dd = sqrtf(fmaxf(d2, 0.f));
        const float S = (i == j) ? 0.f : -2.f * dd;
        const int di = idxi - idxj[n];
        const unsigned diff = (unsigned)(di < 0 ? -di : di);
        // v3 via modular-inverse divisibility: /243(+5), /27(+3), /3(+1), /3(+1)
        unsigned dq = diff, qq;
        int vv = 0;
        qq = dq * 3534952507u; { const bool b = qq <= 17674762u;   dq = b ? qq : dq; vv += b ? 5 : 0; }
        qq = dq * 1749801491u; { const bool b = qq <= 159072862u;  dq = b ? qq : dq; vv += b ? 3 : 0; }
        qq = dq * 2863311531u; { const bool b = qq <= 1431655765u; dq = b ? qq : dq; vv += b ? 1 : 0; }
        qq = dq * 2863311531u; { const bool b = qq <= 1431655765u; vv += b ? 1 : 0; }
        vv = (diff == 0u) ? 11 : vv;
        const float2 wt = lut[vv];  // (w, w*Pl)
        const float wS = wt.x * S;
        ws += wS; zz += wt.x; wpl += wt.y;
        cws[n] += wS; czz[n] += wt.x; cpl[n] += wt.y;
      }
      // row reduce across the 16 lanes holding this C-row (lane bits 0..3)
#pragma unroll
      for (int o = 1; o < 16; o <<= 1) {
        ws += __shfl_xor(ws, o, 64);
        zz += __shfl_xor(zz, o, 64);
        wpl += __shfl_xor(wpl, o, 64);
      }
      if (r0 == 0) {
        Pws[(size_t)dslot * N + i] = ws;
        Pz[(size_t)dslot * N + i] = zz;
        Ppl[(size_t)dslot * N + i] = wpl;
      }
    }
  }
  // transposed (column) partials -> rows of block jb, slot 2*ib+wr
  if (ib != jb) {
    const int tslot = ib * 2 + wr;
#pragma unroll
    for (int nn = 0; nn < 4; ++nn) {
      float a = cws[nn], b = czz[nn], c = cpl[nn];
#pragma unroll
      for (int o = 16; o < 64; o <<= 1) {
        a += __shfl_xor(a, o, 64);
        b += __shfl_xor(b, o, 64);
        c += __shfl_xor(c, o, 64);
      }
      if (kg == 0) {
        const int j = jbase + nn * 16;
        Pws[(size_t)tslot * N + j] = a;
        Pz[(size_t)tslot * N + j] = b;
        Ppl[(size_t)tslot * N + j] = c;
      }
    }
  }
}

// Per-row: combine the 128 j-partials (fixed order) -> T_i
__global__ __launch_bounds__(256) void r1_kernel(
    const float* __restrict__ Pws, const float* __restrict__ Pz,
    const float* __restrict__ Ppl, float* __restrict__ t) {
  const int row = blockIdx.x * 256 + threadIdx.x;
  float ws = 0.f, zz = 0.f, wpl = 0.f;
  for (int s = 0; s < 128; ++s) {
    ws += Pws[(size_t)s * N + row];
    zz += Pz[(size_t)s * N + row];
    wpl += Ppl[(size_t)s * N + row];
  }
  t[row] = (wpl - ws) / zz - logf(zz);
}

// Final deterministic scalar reduction.
__global__ __launch_bounds__(256) void r2_kernel(const float* __restrict__ t,
                                                 float* __restrict__ out) {
  __shared__ float red[256];
  float s = 0.f;
  for (int r = threadIdx.x; r < N; r += 256) s += t[r];
  red[threadIdx.x] = s;
  __syncthreads();
  for (int o = 128; o > 0; o >>= 1) {
    if (threadIdx.x < (unsigned)o) red[threadIdx.x] += red[threadIdx.x + o];
    __syncthreads();
  }
  if (threadIdx.x == 0) out[0] = red[0] / (float)N;
}

extern "C" void kernel_launch(void* const* d_in, const int* in_sizes, int n_in,
                              void* d_out, int out_size, void* d_ws, size_t ws_size,
                              hipStream_t stream) {
  const float* z = (const float*)d_in[0];
  const int* idx = (const int*)d_in[1];
  float* out = (float*)d_out;
  char* ws = (char*)d_ws;
  // workspace layout (~44.2 MB total); zh and zl MUST be adjacent (Kext view)
  unsigned short* zh = (unsigned short*)ws;                            // 16 MB
  unsigned short* zl = zh + (size_t)N * D;                             // 16 MB
  float* sq = (float*)(ws + ((size_t)32 << 20));                       // 32 KB
  float* Pws = (float*)(ws + ((size_t)32 << 20) + ((size_t)64 << 10)); // 4 MB
  float* Pz = Pws + (size_t)128 * N;                                   // 4 MB
  float* Ppl = Pz + (size_t)128 * N;                                   // 4 MB
  float* tt = Ppl + (size_t)128 * N;                                   // 32 KB

  prep_kernel<<<N, 256, 0, stream>>>(z, zh, zl, sq);
  gram_kernel<<<64 * 65 / 2, 256, 0, stream>>>(zh, sq, idx, Pws, Pz, Ppl);
  r1_kernel<<<N / 256, 256, 0, stream>>>(Pws, Pz, Ppl, tt);
  r2_kernel<<<1, 256, 0, stream>>>(tt, out);
}

// Round 6
// 251.629 us; speedup vs baseline: 1.1791x; 1.1791x over previous
//
#include <hip/hip_runtime.h>
#include <hip/hip_bf16.h>
#include <math.h>

#define GLOBAL_AS __attribute__((address_space(1)))
#define LDS_AS __attribute__((address_space(3)))

typedef __bf16 bf16x8 __attribute__((ext_vector_type(8)));
typedef float f32x4 __attribute__((ext_vector_type(4)));

#define N 8192
#define D 1024

__device__ __forceinline__ unsigned short f2bf_rne(float f) {
  unsigned u = __float_as_uint(f);
  unsigned r = u + 0x7FFFu + ((u >> 16) & 1u);
  return (unsigned short)(r >> 16);
}

// Convert z (fp32) -> z_hi + z_lo (bf16 split), and row sums of squares.
// zh and zl are adjacent: zl = zh + N*D, forming a [N][2048] "extended" bf16
// matrix whose gram = hi.hi + hi.lo + lo.hi + lo.lo ~= fp32 gram.
__global__ __launch_bounds__(256) void prep_kernel(
    const float* __restrict__ z, unsigned short* __restrict__ zh,
    unsigned short* __restrict__ zl, float* __restrict__ sq) {
  const int r = blockIdx.x, t = threadIdx.x;
  const float4 v = *(const float4*)(z + (size_t)r * D + t * 4);
  float f[4] = {v.x, v.y, v.z, v.w};
  unsigned short hh[4], ll[4];
  float s = 0.f;
#pragma unroll
  for (int u = 0; u < 4; ++u) {
    float x = f[u];
    s = fmaf(x, x, s);
    unsigned short hb = f2bf_rne(x);
    float hf = __uint_as_float(((unsigned)hb) << 16);
    hh[u] = hb;
    ll[u] = f2bf_rne(x - hf);
  }
  *(ushort4*)(zh + (size_t)r * D + t * 4) = make_ushort4(hh[0], hh[1], hh[2], hh[3]);
  *(ushort4*)(zl + (size_t)r * D + t * 4) = make_ushort4(ll[0], ll[1], ll[2], ll[3]);
  // deterministic block reduction
#pragma unroll
  for (int o = 32; o >= 1; o >>= 1) s += __shfl_down(s, o, 64);
  __shared__ float red[4];
  const int lane = t & 63, wv = t >> 6;
  if (lane == 0) red[wv] = s;
  __syncthreads();
  if (t == 0) sq[r] = ((red[0] + red[1]) + red[2]) + red[3];
}

// Lower-triangle 128x128 tile gram over Kext=2048, BK=64, fused KL epilogue.
// Occupancy strategy (r4/r5 lessons): loop live set trimmed to ~1 staging
// VGPR (SGPR tile bases via readfirstlane, compile-time per-inst deltas,
// scalar k-advance) + 2 LDS-read bases + 32 frag + 64 acc -> fits the
// (256,3) cap of 170 unified regs WITHOUT spill; 32 MFMA per barrier-pair
// (2x r5's amortization).
// Swizzle: LDS unit (rr, cs) holds global unit (rr, cs ^ (rr&7)); read at
// unit (kc*4+kg) ^ (row&7) -> 8 lanes per bank-group, conflict-free.
__global__ __launch_bounds__(256, 3) void gram_kernel(
    const unsigned short* __restrict__ zh,
    const float* __restrict__ sq, const int* __restrict__ idx,
    float* __restrict__ Pws, float* __restrict__ Pz, float* __restrict__ Ppl) {
  __shared__ __align__(16) unsigned short lds[2 * 128 * 64];  // A, B (32 KiB)
  __shared__ float2 lut[12];  // (w, w*Pl) per v3 value; [11] = diff==0 case
  // triangle decode: blockIdx.x = ib*(ib+1)/2 + jb, jb <= ib
  const int t = blockIdx.x;
  int ibv = (int)((sqrtf(8.f * (float)t + 1.f) - 1.f) * 0.5f);
  while ((ibv + 1) * (ibv + 2) / 2 <= t) ++ibv;
  while (ibv * (ibv + 1) / 2 > t) --ibv;
  const int ib = __builtin_amdgcn_readfirstlane(ibv);
  const int jb = __builtin_amdgcn_readfirstlane(t - ibv * (ibv + 1) / 2);

  const int tid = threadIdx.x;
  const int lane = tid & 63, wv = tid >> 6;
  const int wr = wv >> 1, wc = wv & 1;
  const int r0 = lane & 15, kg = lane >> 4;

  if (tid < 12) {
    const float Pl = (tid == 11) ? 0.f : -2.f * exp2f(-1.5849625007211562f * (float)tid);
    const float w = exp2f(1.4426950408889634f * Pl);
    lut[tid] = make_float2(w, w * Pl);
  }

  // --- staging addressing (1 live VGPR) ---
  // inst i4 covers rows i4*32+(tid>>3) of the tile; unit col cs = tid&7;
  // source col unit c = cs ^ (rr&7) (rr&7 == (tid>>3)&7, i4*32 = 0 mod 8).
  const unsigned vbase =
      ((unsigned)(tid >> 3) * 2048u) + ((unsigned)((tid & 7) ^ ((tid >> 3) & 7)) * 16u);
  const char* aBase = (const char*)(zh + (size_t)ib * 128 * D);
  const char* bBase = (const char*)(zh + (size_t)jb * 128 * D);
  char* ldsc = (char*)&lds[0];

  // --- LDS read addressing (2 live VGPRs; kc=1 = base ^ 64) ---
  const int ub = kg ^ (r0 & 3);          // unit bits 0..1
  const int kcx = (r0 >> 2) & 1;         // unit bit 2 xor source (row&4)
  const unsigned aoff0 = (unsigned)((wr * 64 + r0) * 128 + (kcx * 4 + ub) * 16);
  const unsigned boff0 = (unsigned)(16384 + (wc * 64 + r0) * 128 + (kcx * 4 + ub) * 16);

  f32x4 acc[4][4];
  const f32x4 vz = {0.f, 0.f, 0.f, 0.f};
#pragma unroll
  for (int m = 0; m < 4; ++m)
#pragma unroll
    for (int n = 0; n < 4; ++n) acc[m][n] = vz;

  // Kext = 2048: two segments (hi, lo) x 16 steps of BK=64 (128B)
#pragma unroll 1
  for (int seg = 0; seg < 2; ++seg) {
    const size_t segoff = (size_t)seg * ((size_t)N * D * 2);
#pragma unroll 1
    for (int ks = 0; ks < 16; ++ks) {
      const char* aS = aBase + segoff + (unsigned)(ks * 128);
      const char* bS = bBase + segoff + (unsigned)(ks * 128);
      __syncthreads();
#pragma unroll
      for (int i4 = 0; i4 < 4; ++i4)
        __builtin_amdgcn_global_load_lds(
            (const GLOBAL_AS void*)(aS + (unsigned)(i4 * 65536) + vbase),
            (LDS_AS void*)(ldsc + i4 * 4096 + tid * 16), 16, 0, 0);
#pragma unroll
      for (int i4 = 0; i4 < 4; ++i4)
        __builtin_amdgcn_global_load_lds(
            (const GLOBAL_AS void*)(bS + (unsigned)(i4 * 65536) + vbase),
            (LDS_AS void*)(ldsc + 16384 + i4 * 4096 + tid * 16), 16, 0, 0);
      __syncthreads();

      {  // kc = 0
        bf16x8 a[4], b[4];
#pragma unroll
        for (int m = 0; m < 4; ++m) a[m] = *(const bf16x8*)(ldsc + aoff0 + m * 2048);
#pragma unroll
        for (int n = 0; n < 4; ++n) b[n] = *(const bf16x8*)(ldsc + boff0 + n * 2048);
#pragma unroll
        for (int m = 0; m < 4; ++m)
#pragma unroll
          for (int n = 0; n < 4; ++n)
            acc[m][n] = __builtin_amdgcn_mfma_f32_16x16x32_bf16(a[m], b[n], acc[m][n], 0, 0, 0);
      }
      {  // kc = 1 (unit bit2 flip = byte bit6; row bits start at bit7)
        const unsigned aoff1 = aoff0 ^ 64u, boff1 = boff0 ^ 64u;
        bf16x8 a[4], b[4];
#pragma unroll
        for (int m = 0; m < 4; ++m) a[m] = *(const bf16x8*)(ldsc + aoff1 + m * 2048);
#pragma unroll
        for (int n = 0; n < 4; ++n) b[n] = *(const bf16x8*)(ldsc + boff1 + n * 2048);
#pragma unroll
        for (int m = 0; m < 4; ++m)
#pragma unroll
          for (int n = 0; n < 4; ++n)
            acc[m][n] = __builtin_amdgcn_mfma_f32_16x16x32_bf16(a[m], b[n], acc[m][n], 0, 0, 0);
      }
    }
  }

  // ---- Epilogue: S = -2*sqrt(max(sq_i+sq_j-2g,0)); padic weights; partials ----
  const int ibase = ib * 128 + wr * 64 + kg * 4;
  const int jbase = jb * 128 + wc * 64 + r0;
  float sqj[4];
  int idxj[4];
#pragma unroll
  for (int n = 0; n < 4; ++n) {
    sqj[n] = sq[jbase + n * 16];
    idxj[n] = idx[jbase + n * 16];
  }
  const int dslot = jb * 2 + wc;
  // column (transposed) accumulators: per n, summed over this lane's (m,q) i-set
  float cws[4] = {0.f, 0.f, 0.f, 0.f};
  float czz[4] = {0.f, 0.f, 0.f, 0.f};
  float cpl[4] = {0.f, 0.f, 0.f, 0.f};
#pragma unroll
  for (int m = 0; m < 4; ++m) {
#pragma unroll
    for (int q = 0; q < 4; ++q) {
      const int i = ibase + m * 16 + q;
      const float sqi = sq[i];
      const int idxi = idx[i];
      float ws = 0.f, zz = 0.f, wpl = 0.f;
#pragma unroll
      for (int n = 0; n < 4; ++n) {
        const int j = jbase + n * 16;
        const float g = acc[m][n][q];
        const float d2 = sqi + sqj[n] - 2.f * g;
        const float dd = sqrtf(fmaxf(d2, 0.f));
        const float S = (i == j) ? 0.f : -2.f * dd;
        const int di = idxi - idxj[n];
        const unsigned diff = (unsigned)(di < 0 ? -di : di);
        // v3 via modular-inverse divisibility: /243(+5), /27(+3), /3(+1), /3(+1)
        unsigned dq = diff, qq;
        int vv = 0;
        qq = dq * 3534952507u; { const bool b = qq <= 17674762u;   dq = b ? qq : dq; vv += b ? 5 : 0; }
        qq = dq * 1749801491u; { const bool b = qq <= 159072862u;  dq = b ? qq : dq; vv += b ? 3 : 0; }
        qq = dq * 2863311531u; { const bool b = qq <= 1431655765u; dq = b ? qq : dq; vv += b ? 1 : 0; }
        qq = dq * 2863311531u; { const bool b = qq <= 1431655765u; vv += b ? 1 : 0; }
        vv = (diff == 0u) ? 11 : vv;
        const float2 wt = lut[vv];  // (w, w*Pl)
        const float wS = wt.x * S;
        ws += wS; zz += wt.x; wpl += wt.y;
        cws[n] += wS; czz[n] += wt.x; cpl[n] += wt.y;
      }
      // row reduce across the 16 lanes holding this C-row (lane bits 0..3)
#pragma unroll
      for (int o = 1; o < 16; o <<= 1) {
        ws += __shfl_xor(ws, o, 64);
        zz += __shfl_xor(zz, o, 64);
        wpl += __shfl_xor(wpl, o, 64);
      }
      if (r0 == 0) {
        Pws[(size_t)dslot * N + i] = ws;
        Pz[(size_t)dslot * N + i] = zz;
        Ppl[(size_t)dslot * N + i] = wpl;
      }
    }
  }
  // transposed (column) partials -> rows of block jb, slot 2*ib+wr
  if (ib != jb) {
    const int tslot = ib * 2 + wr;
#pragma unroll
    for (int nn = 0; nn < 4; ++nn) {
      float a = cws[nn], b = czz[nn], c = cpl[nn];
#pragma unroll
      for (int o = 16; o < 64; o <<= 1) {
        a += __shfl_xor(a, o, 64);
        b += __shfl_xor(b, o, 64);
        c += __shfl_xor(c, o, 64);
      }
      if (kg == 0) {
        const int j = jbase + nn * 16;
        Pws[(size_t)tslot * N + j] = a;
        Pz[(size_t)tslot * N + j] = b;
        Ppl[(size_t)tslot * N + j] = c;
      }
    }
  }
}

// Per-row: combine the 128 j-partials (fixed order) -> T_i
__global__ __launch_bounds__(256) void r1_kernel(
    const float* __restrict__ Pws, const float* __restrict__ Pz,
    const float* __restrict__ Ppl, float* __restrict__ t) {
  const int row = blockIdx.x * 256 + threadIdx.x;
  float ws = 0.f, zz = 0.f, wpl = 0.f;
  for (int s = 0; s < 128; ++s) {
    ws += Pws[(size_t)s * N + row];
    zz += Pz[(size_t)s * N + row];
    wpl += Ppl[(size_t)s * N + row];
  }
  t[row] = (wpl - ws) / zz - logf(zz);
}

// Final deterministic scalar reduction.
__global__ __launch_bounds__(256) void r2_kernel(const float* __restrict__ t,
                                                 float* __restrict__ out) {
  __shared__ float red[256];
  float s = 0.f;
  for (int r = threadIdx.x; r < N; r += 256) s += t[r];
  red[threadIdx.x] = s;
  __syncthreads();
  for (int o = 128; o > 0; o >>= 1) {
    if (threadIdx.x < (unsigned)o) red[threadIdx.x] += red[threadIdx.x + o];
    __syncthreads();
  }
  if (threadIdx.x == 0) out[0] = red[0] / (float)N;
}

extern "C" void kernel_launch(void* const* d_in, const int* in_sizes, int n_in,
                              void* d_out, int out_size, void* d_ws, size_t ws_size,
                              hipStream_t stream) {
  const float* z = (const float*)d_in[0];
  const int* idx = (const int*)d_in[1];
  float* out = (float*)d_out;
  char* ws = (char*)d_ws;
  // workspace layout (~44.2 MB total); zh and zl MUST be adjacent (Kext view)
  unsigned short* zh = (unsigned short*)ws;                            // 16 MB
  unsigned short* zl = zh + (size_t)N * D;                             // 16 MB
  float* sq = (float*)(ws + ((size_t)32 << 20));                       // 32 KB
  float* Pws = (float*)(ws + ((size_t)32 << 20) + ((size_t)64 << 10)); // 4 MB
  float* Pz = Pws + (size_t)128 * N;                                   // 4 MB
  float* Ppl = Pz + (size_t)128 * N;                                   // 4 MB
  float* tt = Ppl + (size_t)128 * N;                                   // 32 KB

  prep_kernel<<<N, 256, 0, stream>>>(z, zh, zl, sq);
  gram_kernel<<<64 * 65 / 2, 256, 0, stream>>>(zh, sq, idx, Pws, Pz, Ppl);
  r1_kernel<<<N / 256, 256, 0, stream>>>(Pws, Pz, Ppl, tt);
  r2_kernel<<<1, 256, 0, stream>>>(tt, out);
}